// Round 1
// baseline (1250.555 us; speedup 1.0000x reference)
//
#include <hip/hip_runtime.h>
#include <math.h>

typedef __bf16 bf16x8 __attribute__((ext_vector_type(8)));
typedef float  f32x4  __attribute__((ext_vector_type(4)));

#define DEVFN __device__ __forceinline__

DEVFN unsigned short f2bf(float f) {
    union { float f; unsigned u; } v; v.f = f;
    unsigned r = v.u + 0x7FFFu + ((v.u >> 16) & 1u);   // RNE
    return (unsigned short)(r >> 16);
}
DEVFN float sigmoidf_(float x) { return 1.0f / (1.0f + expf(-x)); }

// ---------------------------------------------------------------- LSTM ----
// one block per batch element; 512 threads = one per gate row
__global__ void lstm_kernel(const int* __restrict__ qidx, const float* __restrict__ emb,
                            const float* __restrict__ Wih, const float* __restrict__ Whh,
                            const float* __restrict__ bih, const float* __restrict__ bhh,
                            const float* __restrict__ h0, const float* __restrict__ c0,
                            float* __restrict__ qst)
{
    int b = blockIdx.x, tid = threadIdx.x;
    __shared__ float hs[128], cs[128], xs[32], gs[512];
    if (tid < 128) { hs[tid] = h0[b*128 + tid]; cs[tid] = c0[b*128 + tid]; }
    float bsum = bih[tid] + bhh[tid];
    for (int t = 0; t < 18; ++t) {
        if (tid < 32) {
            int id = qidx[b*18 + t];
            xs[tid] = (id != 0) ? emb[id*32 + tid] : 0.0f;
        }
        __syncthreads();
        float g = bsum;
        const float* wi = Wih + tid*32;
        #pragma unroll
        for (int d = 0; d < 32; ++d) g += xs[d] * wi[d];
        const float* wh = Whh + tid*128;
        for (int d = 0; d < 128; ++d) g += hs[d] * wh[d];
        gs[tid] = g;
        __syncthreads();
        if (tid < 128) {
            float ig = sigmoidf_(gs[tid]);
            float fg = sigmoidf_(gs[128 + tid]);
            float gg = tanhf(gs[256 + tid]);
            float og = sigmoidf_(gs[384 + tid]);
            float cn = fg * cs[tid] + ig * gg;
            cs[tid] = cn;
            hs[tid] = og * tanhf(cn);
        }
        __syncthreads();
    }
    if (tid < 128) qst[b*128 + tid] = cs[tid];   // final CELL state
}

// ---------------------------------------------------------------- conv ----
// direct conv 3x3 stride2 pad1, Co=24, B=64. ab = per-input-channel BN
// scale/offset (a[Cin], bb[Cin]) folded from previous layer's stats, or null.
__global__ void conv_kernel(const float* __restrict__ in, const float* __restrict__ wk,
                            const float* __restrict__ cb, const float* __restrict__ ab,
                            float* __restrict__ out,
                            int Cin, int Hin, int Win, int Hout, int Wout)
{
    int idx = blockIdx.x * blockDim.x + threadIdx.x;
    int total = 64 * 24 * Hout * Wout;
    if (idx >= total) return;
    int ow = idx % Wout;
    int oh = (idx / Wout) % Hout;
    int co = (idx / (Wout * Hout)) % 24;
    int b  = idx / (Wout * Hout * 24);
    float acc = cb[co];
    for (int ci = 0; ci < Cin; ++ci) {
        float a_ = 1.0f, o_ = 0.0f;
        if (ab) { a_ = ab[ci]; o_ = ab[Cin + ci]; }
        const float* ip = in + ((size_t)(b*Cin + ci)) * Hin * Win;
        const float* wp = wk + (co*Cin + ci) * 9;
        #pragma unroll
        for (int kh = 0; kh < 3; ++kh) {
            int ih = oh*2 + kh - 1;
            if (ih < 0 || ih >= Hin) continue;
            #pragma unroll
            for (int kw = 0; kw < 3; ++kw) {
                int iw = ow*2 + kw - 1;
                if (iw < 0 || iw >= Win) continue;
                acc += (ip[ih*Win + iw] * a_ + o_) * wp[kh*3 + kw];
            }
        }
    }
    out[idx] = fmaxf(acc, 0.0f);   // bias+relu (pre-BN) stored
}

// per-channel train-mode BN stats over (B,H,W) -> folded scale/offset
__global__ void bn_stats_kernel(const float* __restrict__ y, const float* __restrict__ gamma,
                                const float* __restrict__ beta, float* __restrict__ ab, int HW)
{
    int c = blockIdx.x, tid = threadIdx.x;
    int N = 64 * HW;
    float s = 0.f, s2 = 0.f;
    for (int i = tid; i < N; i += 256) {
        int b = i / HW, p = i - b * HW;
        float v = y[((size_t)(b*24 + c)) * HW + p];
        s += v; s2 += v * v;
    }
    __shared__ float rs[256], rs2[256];
    rs[tid] = s; rs2[tid] = s2;
    __syncthreads();
    for (int st = 128; st > 0; st >>= 1) {
        if (tid < st) { rs[tid] += rs[tid + st]; rs2[tid] += rs2[tid + st]; }
        __syncthreads();
    }
    if (tid == 0) {
        float m = rs[0] / N;
        float v = rs2[0] / N - m * m;               // biased var
        float r = rsqrtf(v + 1e-5f);
        float a = gamma[c] * r;
        ab[c] = a; ab[24 + c] = beta[c] - m * a;
    }
}

// --------------------------------------------------------------- xf -------
__global__ void build_xf_kernel(const float* __restrict__ y4, const float* __restrict__ ab4,
                                float* __restrict__ xf)
{
    int b = blockIdx.x, p = threadIdx.x;          // 64 x 64
    float* o = xf + ((size_t)(b*64 + p)) * 26;
    for (int c = 0; c < 24; ++c)
        o[c] = y4[((size_t)(b*24 + c)) * 64 + p] * ab4[c] + ab4[24 + c];
    o[24] = ((float)p / 8.0f - 4.0f) * 0.25f;     // python true division i/D
    o[25] = ((float)(p % 8) - 4.0f) * 0.25f;      // integer i%D
}

// Ai[b,j,c], Aj[b,j,c], Q[b,c] — decomposed first g-layer
__global__ void aiajq_kernel(const float* __restrict__ xf, const float* __restrict__ qst,
                             const float* __restrict__ Wg1, const float* __restrict__ bg1,
                             float* __restrict__ Ai, float* __restrict__ Aj, float* __restrict__ Q)
{
    int b = blockIdx.x, c = threadIdx.x;          // 64 x 256
    __shared__ float xfl[64 * 26];
    __shared__ float qv[128];
    for (int i = c; i < 64*26; i += 256) xfl[i] = xf[(size_t)b*64*26 + i];
    if (c < 128) qv[c] = qst[b*128 + c];
    __syncthreads();
    const float* w = Wg1 + (size_t)c * 180;
    float wa[26], wb[26];
    #pragma unroll
    for (int d = 0; d < 26; ++d) { wa[d] = w[d]; wb[d] = w[26 + d]; }
    float q = bg1[c];
    for (int d = 0; d < 128; ++d) q += qv[d] * w[52 + d];
    Q[b*256 + c] = q;
    for (int j = 0; j < 64; ++j) {
        const float* xr = xfl + j*26;
        float sa = 0.f, sb = 0.f;
        #pragma unroll
        for (int d = 0; d < 26; ++d) { sa += xr[d]*wa[d]; sb += xr[d]*wb[d]; }
        Ai[((size_t)(b*64 + j))*256 + c] = sa;
        Aj[((size_t)(b*64 + j))*256 + c] = sb;
    }
}

__global__ void cvt_bf16_kernel(const float* __restrict__ src, unsigned short* __restrict__ dst, int n)
{
    int i = blockIdx.x * 256 + threadIdx.x;
    if (i < n) dst[i] = f2bf(src[i]);
}

// --------------------------------------------------------------- g-MLP ----
// one block per (b,k): 64 pair-rows, 3 fused bf16-MFMA layers, column-sum out
__launch_bounds__(256, 2)
__global__ void gmlp_kernel(const float* __restrict__ Ai, const float* __restrict__ Aj,
                            const float* __restrict__ Q,
                            const unsigned short* __restrict__ Wb2, const float* __restrict__ bg2,
                            const unsigned short* __restrict__ Wb3, const float* __restrict__ bg3,
                            const unsigned short* __restrict__ Wb4, const float* __restrict__ bg4,
                            float* __restrict__ partial)
{
    constexpr int LDP = 264;                       // +8 pad: 2-way bank alias (free)
    __shared__ __align__(16) unsigned short bufA[64 * LDP];
    __shared__ __align__(16) unsigned short bufB[64 * LDP];
    int tid = threadIdx.x;
    int blk = blockIdx.x;
    int b = blk >> 6;

    // ---- h1 = relu(Ai[b,j] + Aj[b,k] + Q[b]) -> bufA (bf16)
    float ajq = Aj[(size_t)blk * 256 + tid] + Q[b*256 + tid];
    const float* aip = Ai + ((size_t)b * 64) * 256 + tid;
    for (int j = 0; j < 64; ++j) {
        float v = aip[(size_t)j * 256] + ajq;
        bufA[j * LDP + tid] = f2bf(fmaxf(v, 0.f));
    }
    __syncthreads();

    int l = tid & 63, w = tid >> 6;
    int lr = l & 15, lg = l >> 4;
    int wcol = w * 64;                              // wave's 64-col slice

    const unsigned short* Ws[3] = {Wb2, Wb3, Wb4};
    const float* Bs[3] = {bg2, bg3, bg4};
    unsigned short* inb = bufA;
    unsigned short* outb = bufB;

    for (int layer = 0; layer < 3; ++layer) {
        const unsigned short* W = Ws[layer];
        const float* bias = Bs[layer];
        f32x4 acc[4][4];
        #pragma unroll
        for (int i = 0; i < 4; ++i)
            #pragma unroll
            for (int j2 = 0; j2 < 4; ++j2) { f32x4 z = {0.f,0.f,0.f,0.f}; acc[i][j2] = z; }

        #pragma unroll
        for (int kk = 0; kk < 256; kk += 32) {
            int ko = kk + lg * 8;
            bf16x8 aF[4], bF[4];
            #pragma unroll
            for (int rg = 0; rg < 4; ++rg)
                aF[rg] = *reinterpret_cast<const bf16x8*>(&inb[(rg*16 + lr) * LDP + ko]);
            #pragma unroll
            for (int cg = 0; cg < 4; ++cg)
                bF[cg] = *reinterpret_cast<const bf16x8*>(&W[(size_t)(wcol + cg*16 + lr) * 256 + ko]);
            #pragma unroll
            for (int rg = 0; rg < 4; ++rg)
                #pragma unroll
                for (int cg = 0; cg < 4; ++cg)
                    acc[rg][cg] = __builtin_amdgcn_mfma_f32_16x16x32_bf16(aF[rg], bF[cg], acc[rg][cg], 0, 0, 0);
        }

        if (layer < 2) {
            #pragma unroll
            for (int cg = 0; cg < 4; ++cg) {
                int col = wcol + cg*16 + lr;
                float bc = bias[col];
                #pragma unroll
                for (int rg = 0; rg < 4; ++rg)
                    #pragma unroll
                    for (int r = 0; r < 4; ++r) {
                        int row = rg*16 + lg*4 + r;   // C/D: row=(lane>>4)*4+reg
                        outb[row * LDP + col] = f2bf(fmaxf(acc[rg][cg][r] + bc, 0.f));
                    }
            }
            __syncthreads();
            unsigned short* t = inb; inb = outb; outb = t;
        } else {
            // layer 4: relu then column-sum over the block's 64 rows
            #pragma unroll
            for (int cg = 0; cg < 4; ++cg) {
                int col = wcol + cg*16 + lr;
                float bc = bias[col];
                float cssum = 0.f;
                #pragma unroll
                for (int rg = 0; rg < 4; ++rg)
                    #pragma unroll
                    for (int r = 0; r < 4; ++r)
                        cssum += fmaxf(acc[rg][cg][r] + bc, 0.f);
                cssum += __shfl_xor(cssum, 16, 64);
                cssum += __shfl_xor(cssum, 32, 64);
                if (lg == 0)
                    partial[(size_t)blk * 256 + col] = cssum;
            }
        }
    }
}

__global__ void reduce_partial_kernel(const float* __restrict__ partial, float* __restrict__ xg)
{
    int b = blockIdx.x, c = threadIdx.x;
    float s = 0.f;
    const float* p = partial + ((size_t)b * 64) * 256 + c;
    for (int k = 0; k < 64; ++k) s += p[(size_t)k * 256];
    xg[b*256 + c] = s;
}

// --------------------------------------------------------------- f-MLP ----
__global__ void fmlp_kernel(const float* __restrict__ xg,
                            const float* __restrict__ Wf1, const float* __restrict__ bf1,
                            const float* __restrict__ Wf2, const float* __restrict__ bf2,
                            const float* __restrict__ Wf3, const float* __restrict__ bf3,
                            float* __restrict__ out)
{
    int b = blockIdx.x, tid = threadIdx.x;
    __shared__ float v0[256], v1[256], lgt[28];
    v0[tid] = xg[b*256 + tid];
    __syncthreads();
    {
        float s = bf1[tid];
        const float4* wr = reinterpret_cast<const float4*>(Wf1 + (size_t)tid * 256);
        for (int k4 = 0; k4 < 64; ++k4) {
            float4 wv = wr[k4];
            s += wv.x*v0[k4*4+0] + wv.y*v0[k4*4+1] + wv.z*v0[k4*4+2] + wv.w*v0[k4*4+3];
        }
        v1[tid] = fmaxf(s, 0.f);
    }
    __syncthreads();
    {
        float s = bf2[tid];
        const float4* wr = reinterpret_cast<const float4*>(Wf2 + (size_t)tid * 256);
        for (int k4 = 0; k4 < 64; ++k4) {
            float4 wv = wr[k4];
            s += wv.x*v1[k4*4+0] + wv.y*v1[k4*4+1] + wv.z*v1[k4*4+2] + wv.w*v1[k4*4+3];
        }
        v0[tid] = fmaxf(s, 0.f);
    }
    __syncthreads();
    if (tid < 28) {
        float s = bf3[tid];
        const float4* wr = reinterpret_cast<const float4*>(Wf3 + (size_t)tid * 256);
        for (int k4 = 0; k4 < 64; ++k4) {
            float4 wv = wr[k4];
            s += wv.x*v0[k4*4+0] + wv.y*v0[k4*4+1] + wv.z*v0[k4*4+2] + wv.w*v0[k4*4+3];
        }
        lgt[tid] = s;
    }
    __syncthreads();
    if (tid == 0) {
        float mx = -1e30f;
        for (int i = 0; i < 28; ++i) mx = fmaxf(mx, lgt[i]);
        float se = 0.f;
        for (int i = 0; i < 28; ++i) se += expf(lgt[i] - mx);
        float lse = mx + logf(se);
        for (int i = 0; i < 28; ++i) out[b*28 + i] = lgt[i] - lse;
    }
}

// ------------------------------------------------------------- launch -----
extern "C" void kernel_launch(void* const* d_in, const int* in_sizes, int n_in,
                              void* d_out, int out_size, void* d_ws, size_t ws_size,
                              hipStream_t stream)
{
    (void)in_sizes; (void)n_in; (void)out_size; (void)ws_size;
    const float* img = (const float*)d_in[0];
    const int*   qidx= (const int*)  d_in[1];
    const float* emb = (const float*)d_in[2];
    const float* Wih = (const float*)d_in[3];
    const float* Whh = (const float*)d_in[4];
    const float* bih = (const float*)d_in[5];
    const float* bhh = (const float*)d_in[6];
    const float* k1  = (const float*)d_in[7];  const float* cb1=(const float*)d_in[8];
    const float* g1  = (const float*)d_in[9];  const float* be1=(const float*)d_in[10];
    const float* k2  = (const float*)d_in[11]; const float* cb2=(const float*)d_in[12];
    const float* g2  = (const float*)d_in[13]; const float* be2=(const float*)d_in[14];
    const float* k3  = (const float*)d_in[15]; const float* cb3=(const float*)d_in[16];
    const float* g3  = (const float*)d_in[17]; const float* be3=(const float*)d_in[18];
    const float* k4  = (const float*)d_in[19]; const float* cb4=(const float*)d_in[20];
    const float* g4  = (const float*)d_in[21]; const float* be4=(const float*)d_in[22];
    const float* Wg1 = (const float*)d_in[23]; const float* bg1=(const float*)d_in[24];
    const float* Wg2 = (const float*)d_in[25]; const float* bg2=(const float*)d_in[26];
    const float* Wg3 = (const float*)d_in[27]; const float* bg3=(const float*)d_in[28];
    const float* Wg4 = (const float*)d_in[29]; const float* bg4=(const float*)d_in[30];
    const float* Wf1 = (const float*)d_in[31]; const float* bf1=(const float*)d_in[32];
    const float* Wf2 = (const float*)d_in[33]; const float* bf2=(const float*)d_in[34];
    const float* Wf3 = (const float*)d_in[35]; const float* bf3=(const float*)d_in[36];
    const float* h0  = (const float*)d_in[37]; const float* c0 =(const float*)d_in[38];
    float* out = (float*)d_out;

    // workspace carve-up (floats), all 16B aligned
    float* ws = (float*)d_ws;
    float* y1 = ws;   ws += 64*24*64*64;
    float* y2 = ws;   ws += 64*24*32*32;
    float* y3 = ws;   ws += 64*24*16*16;
    float* y4 = ws;   ws += 64*24*8*8;
    float* ab1 = ws;  ws += 48;
    float* ab2 = ws;  ws += 48;
    float* ab3 = ws;  ws += 48;
    float* ab4 = ws;  ws += 48;
    float* qst = ws;  ws += 64*128;
    float* xf  = ws;  ws += 64*64*26;
    float* Ai  = ws;  ws += 64*64*256;
    float* Aj  = ws;  ws += 64*64*256;
    float* Qb  = ws;  ws += 64*256;
    unsigned short* Wb2 = (unsigned short*)ws; ws += 65536/2;
    unsigned short* Wb3 = (unsigned short*)ws; ws += 65536/2;
    unsigned short* Wb4 = (unsigned short*)ws; ws += 65536/2;
    float* partial = ws; ws += 4096*256;
    float* xg  = ws;  ws += 64*256;

    lstm_kernel<<<64, 512, 0, stream>>>(qidx, emb, Wih, Whh, bih, bhh, h0, c0, qst);

    conv_kernel<<<(64*24*64*64 + 255)/256, 256, 0, stream>>>(img, k1, cb1, nullptr, y1, 3, 128, 128, 64, 64);
    bn_stats_kernel<<<24, 256, 0, stream>>>(y1, g1, be1, ab1, 64*64);
    conv_kernel<<<(64*24*32*32 + 255)/256, 256, 0, stream>>>(y1, k2, cb2, ab1, y2, 24, 64, 64, 32, 32);
    bn_stats_kernel<<<24, 256, 0, stream>>>(y2, g2, be2, ab2, 32*32);
    conv_kernel<<<(64*24*16*16 + 255)/256, 256, 0, stream>>>(y2, k3, cb3, ab2, y3, 24, 32, 32, 16, 16);
    bn_stats_kernel<<<24, 256, 0, stream>>>(y3, g3, be3, ab3, 16*16);
    conv_kernel<<<(64*24*8*8 + 255)/256, 256, 0, stream>>>(y3, k4, cb4, ab3, y4, 24, 16, 16, 8, 8);
    bn_stats_kernel<<<24, 256, 0, stream>>>(y4, g4, be4, ab4, 8*8);

    build_xf_kernel<<<64, 64, 0, stream>>>(y4, ab4, xf);
    aiajq_kernel<<<64, 256, 0, stream>>>(xf, qst, Wg1, bg1, Ai, Aj, Qb);

    cvt_bf16_kernel<<<256, 256, 0, stream>>>(Wg2, Wb2, 65536);
    cvt_bf16_kernel<<<256, 256, 0, stream>>>(Wg3, Wb3, 65536);
    cvt_bf16_kernel<<<256, 256, 0, stream>>>(Wg4, Wb4, 65536);

    gmlp_kernel<<<4096, 256, 0, stream>>>(Ai, Aj, Qb, Wb2, bg2, Wb3, bg3, Wb4, bg4, partial);
    reduce_partial_kernel<<<64, 256, 0, stream>>>(partial, xg);
    fmlp_kernel<<<64, 256, 0, stream>>>(xg, Wf1, bf1, Wf2, bf2, Wf3, bf3, out);
}

// Round 2
// 836.765 us; speedup vs baseline: 1.4945x; 1.4945x over previous
//
#include <hip/hip_runtime.h>
#include <math.h>

typedef __bf16 bf16x8 __attribute__((ext_vector_type(8)));
typedef float  f32x4  __attribute__((ext_vector_type(4)));

#define DEVFN __device__ __forceinline__

DEVFN unsigned short f2bf(float f) {
    union { float f; unsigned u; } v; v.f = f;
    unsigned r = v.u + 0x7FFFu + ((v.u >> 16) & 1u);   // RNE
    return (unsigned short)(r >> 16);
}
DEVFN float sigmoidf_(float x) { return 1.0f / (1.0f + expf(-x)); }

// ---------------------------------------------------------------- LSTM ----
// one block per batch element; 512 threads = one per gate row
__global__ void lstm_kernel(const int* __restrict__ qidx, const float* __restrict__ emb,
                            const float* __restrict__ Wih, const float* __restrict__ Whh,
                            const float* __restrict__ bih, const float* __restrict__ bhh,
                            const float* __restrict__ h0, const float* __restrict__ c0,
                            float* __restrict__ qst)
{
    int b = blockIdx.x, tid = threadIdx.x;
    __shared__ float hs[128], cs[128], xs[32], gs[512];
    if (tid < 128) { hs[tid] = h0[b*128 + tid]; cs[tid] = c0[b*128 + tid]; }
    float bsum = bih[tid] + bhh[tid];
    for (int t = 0; t < 18; ++t) {
        if (tid < 32) {
            int id = qidx[b*18 + t];
            xs[tid] = (id != 0) ? emb[id*32 + tid] : 0.0f;
        }
        __syncthreads();
        float g = bsum;
        const float* wi = Wih + tid*32;
        #pragma unroll
        for (int d = 0; d < 32; ++d) g += xs[d] * wi[d];
        const float* wh = Whh + tid*128;
        for (int d = 0; d < 128; ++d) g += hs[d] * wh[d];
        gs[tid] = g;
        __syncthreads();
        if (tid < 128) {
            float ig = sigmoidf_(gs[tid]);
            float fg = sigmoidf_(gs[128 + tid]);
            float gg = tanhf(gs[256 + tid]);
            float og = sigmoidf_(gs[384 + tid]);
            float cn = fg * cs[tid] + ig * gg;
            cs[tid] = cn;
            hs[tid] = og * tanhf(cn);
        }
        __syncthreads();
    }
    if (tid < 128) qst[b*128 + tid] = cs[tid];   // final CELL state
}

// ---------------------------------------------------------------- conv ----
// direct conv 3x3 stride2 pad1, Co=24, B=64. ab = per-input-channel BN
// scale/offset (a[Cin], bb[Cin]) folded from previous layer's stats, or null.
__global__ void conv_kernel(const float* __restrict__ in, const float* __restrict__ wk,
                            const float* __restrict__ cb, const float* __restrict__ ab,
                            float* __restrict__ out,
                            int Cin, int Hin, int Win, int Hout, int Wout)
{
    int idx = blockIdx.x * blockDim.x + threadIdx.x;
    int total = 64 * 24 * Hout * Wout;
    if (idx >= total) return;
    int ow = idx % Wout;
    int oh = (idx / Wout) % Hout;
    int co = (idx / (Wout * Hout)) % 24;
    int b  = idx / (Wout * Hout * 24);
    float acc = cb[co];
    for (int ci = 0; ci < Cin; ++ci) {
        float a_ = 1.0f, o_ = 0.0f;
        if (ab) { a_ = ab[ci]; o_ = ab[Cin + ci]; }
        const float* ip = in + ((size_t)(b*Cin + ci)) * Hin * Win;
        const float* wp = wk + (co*Cin + ci) * 9;
        #pragma unroll
        for (int kh = 0; kh < 3; ++kh) {
            int ih = oh*2 + kh - 1;
            if (ih < 0 || ih >= Hin) continue;
            #pragma unroll
            for (int kw = 0; kw < 3; ++kw) {
                int iw = ow*2 + kw - 1;
                if (iw < 0 || iw >= Win) continue;
                acc += (ip[ih*Win + iw] * a_ + o_) * wp[kh*3 + kw];
            }
        }
    }
    out[idx] = fmaxf(acc, 0.0f);   // bias+relu (pre-BN) stored
}

// ---- BN stats, two-stage deterministic reduction -------------------------
// stage 1: grid (24, S); each block reduces batches [s*nb, (s+1)*nb) of its
// channel with float4 coalesced loads.
__global__ void bn_partial_kernel(const float* __restrict__ y, float* __restrict__ part,
                                  int HW, int nb)
{
    int c = blockIdx.x;
    int s = blockIdx.y;
    int S = gridDim.y;
    int tid = threadIdx.x;
    int n4 = HW >> 2;
    float sum = 0.f, sum2 = 0.f;
    for (int b = s * nb; b < (s + 1) * nb; ++b) {
        const float4* p = reinterpret_cast<const float4*>(y + ((size_t)(b*24 + c)) * HW);
        for (int i = tid; i < n4; i += 256) {
            float4 v = p[i];
            sum  += v.x + v.y + v.z + v.w;
            sum2 += v.x*v.x + v.y*v.y + v.z*v.z + v.w*v.w;
        }
    }
    __shared__ float rs[256], rs2[256];
    rs[tid] = sum; rs2[tid] = sum2;
    __syncthreads();
    for (int st = 128; st > 0; st >>= 1) {
        if (tid < st) { rs[tid] += rs[tid + st]; rs2[tid] += rs2[tid + st]; }
        __syncthreads();
    }
    if (tid == 0) {
        part[(c * S + s) * 2]     = rs[0];
        part[(c * S + s) * 2 + 1] = rs2[0];
    }
}

// stage 2: fold into per-channel scale/offset
__global__ void bn_final_kernel(const float* __restrict__ part, const float* __restrict__ gamma,
                                const float* __restrict__ beta, float* __restrict__ ab,
                                int S, int N)
{
    int c = threadIdx.x;
    if (c >= 24) return;
    float s = 0.f, s2 = 0.f;
    for (int i = 0; i < S; ++i) { s += part[(c*S + i)*2]; s2 += part[(c*S + i)*2 + 1]; }
    float m = s / N;
    float v = s2 / N - m * m;               // biased var
    float r = rsqrtf(v + 1e-5f);
    float a = gamma[c] * r;
    ab[c] = a; ab[24 + c] = beta[c] - m * a;
}

// --------------------------------------------------------------- xf -------
__global__ void build_xf_kernel(const float* __restrict__ y4, const float* __restrict__ ab4,
                                float* __restrict__ xf)
{
    int b = blockIdx.x, p = threadIdx.x;          // 64 x 64
    float* o = xf + ((size_t)(b*64 + p)) * 26;
    for (int c = 0; c < 24; ++c)
        o[c] = y4[((size_t)(b*24 + c)) * 64 + p] * ab4[c] + ab4[24 + c];
    o[24] = ((float)p / 8.0f - 4.0f) * 0.25f;     // python true division i/D
    o[25] = ((float)(p % 8) - 4.0f) * 0.25f;      // integer i%D
}

// Ai[b,j,c], Aj[b,j,c], Q[b,c] — decomposed first g-layer
__global__ void aiajq_kernel(const float* __restrict__ xf, const float* __restrict__ qst,
                             const float* __restrict__ Wg1, const float* __restrict__ bg1,
                             float* __restrict__ Ai, float* __restrict__ Aj, float* __restrict__ Q)
{
    int b = blockIdx.x, c = threadIdx.x;          // 64 x 256
    __shared__ float xfl[64 * 26];
    __shared__ float qv[128];
    for (int i = c; i < 64*26; i += 256) xfl[i] = xf[(size_t)b*64*26 + i];
    if (c < 128) qv[c] = qst[b*128 + c];
    __syncthreads();
    const float* w = Wg1 + (size_t)c * 180;
    float wa[26], wb[26];
    #pragma unroll
    for (int d = 0; d < 26; ++d) { wa[d] = w[d]; wb[d] = w[26 + d]; }
    float q = bg1[c];
    for (int d = 0; d < 128; ++d) q += qv[d] * w[52 + d];
    Q[b*256 + c] = q;
    for (int j = 0; j < 64; ++j) {
        const float* xr = xfl + j*26;
        float sa = 0.f, sb = 0.f;
        #pragma unroll
        for (int d = 0; d < 26; ++d) { sa += xr[d]*wa[d]; sb += xr[d]*wb[d]; }
        Ai[((size_t)(b*64 + j))*256 + c] = sa;
        Aj[((size_t)(b*64 + j))*256 + c] = sb;
    }
}

__global__ void cvt_bf16_kernel(const float* __restrict__ src, unsigned short* __restrict__ dst, int n)
{
    int i = blockIdx.x * 256 + threadIdx.x;
    if (i < n) dst[i] = f2bf(src[i]);
}

// --------------------------------------------------------------- g-MLP ----
// one block per (b,k): 64 pair-rows, 3 fused bf16-MFMA layers, column-sum out
__launch_bounds__(256, 2)
__global__ void gmlp_kernel(const float* __restrict__ Ai, const float* __restrict__ Aj,
                            const float* __restrict__ Q,
                            const unsigned short* __restrict__ Wb2, const float* __restrict__ bg2,
                            const unsigned short* __restrict__ Wb3, const float* __restrict__ bg3,
                            const unsigned short* __restrict__ Wb4, const float* __restrict__ bg4,
                            float* __restrict__ partial)
{
    constexpr int LDP = 264;                       // +8 pad: 2-way bank alias (free)
    __shared__ __align__(16) unsigned short bufA[64 * LDP];
    __shared__ __align__(16) unsigned short bufB[64 * LDP];
    int tid = threadIdx.x;
    int blk = blockIdx.x;
    int b = blk >> 6;

    // ---- h1 = relu(Ai[b,j] + Aj[b,k] + Q[b]) -> bufA (bf16)
    float ajq = Aj[(size_t)blk * 256 + tid] + Q[b*256 + tid];
    const float* aip = Ai + ((size_t)b * 64) * 256 + tid;
    for (int j = 0; j < 64; ++j) {
        float v = aip[(size_t)j * 256] + ajq;
        bufA[j * LDP + tid] = f2bf(fmaxf(v, 0.f));
    }
    __syncthreads();

    int l = tid & 63, w = tid >> 6;
    int lr = l & 15, lg = l >> 4;
    int wcol = w * 64;                              // wave's 64-col slice

    const unsigned short* Ws[3] = {Wb2, Wb3, Wb4};
    const float* Bs[3] = {bg2, bg3, bg4};
    unsigned short* inb = bufA;
    unsigned short* outb = bufB;

    for (int layer = 0; layer < 3; ++layer) {
        const unsigned short* W = Ws[layer];
        const float* bias = Bs[layer];
        f32x4 acc[4][4];
        #pragma unroll
        for (int i = 0; i < 4; ++i)
            #pragma unroll
            for (int j2 = 0; j2 < 4; ++j2) { f32x4 z = {0.f,0.f,0.f,0.f}; acc[i][j2] = z; }

        #pragma unroll
        for (int kk = 0; kk < 256; kk += 32) {
            int ko = kk + lg * 8;
            bf16x8 aF[4], bF[4];
            #pragma unroll
            for (int rg = 0; rg < 4; ++rg)
                aF[rg] = *reinterpret_cast<const bf16x8*>(&inb[(rg*16 + lr) * LDP + ko]);
            #pragma unroll
            for (int cg = 0; cg < 4; ++cg)
                bF[cg] = *reinterpret_cast<const bf16x8*>(&W[(size_t)(wcol + cg*16 + lr) * 256 + ko]);
            #pragma unroll
            for (int rg = 0; rg < 4; ++rg)
                #pragma unroll
                for (int cg = 0; cg < 4; ++cg)
                    acc[rg][cg] = __builtin_amdgcn_mfma_f32_16x16x32_bf16(aF[rg], bF[cg], acc[rg][cg], 0, 0, 0);
        }

        if (layer < 2) {
            #pragma unroll
            for (int cg = 0; cg < 4; ++cg) {
                int col = wcol + cg*16 + lr;
                float bc = bias[col];
                #pragma unroll
                for (int rg = 0; rg < 4; ++rg)
                    #pragma unroll
                    for (int r = 0; r < 4; ++r) {
                        int row = rg*16 + lg*4 + r;   // C/D: row=(lane>>4)*4+reg
                        outb[row * LDP + col] = f2bf(fmaxf(acc[rg][cg][r] + bc, 0.f));
                    }
            }
            __syncthreads();
            unsigned short* t = inb; inb = outb; outb = t;
        } else {
            // layer 4: relu then column-sum over the block's 64 rows
            #pragma unroll
            for (int cg = 0; cg < 4; ++cg) {
                int col = wcol + cg*16 + lr;
                float bc = bias[col];
                float cssum = 0.f;
                #pragma unroll
                for (int rg = 0; rg < 4; ++rg)
                    #pragma unroll
                    for (int r = 0; r < 4; ++r)
                        cssum += fmaxf(acc[rg][cg][r] + bc, 0.f);
                cssum += __shfl_xor(cssum, 16, 64);
                cssum += __shfl_xor(cssum, 32, 64);
                if (lg == 0)
                    partial[(size_t)blk * 256 + col] = cssum;
            }
        }
    }
}

__global__ void reduce_partial_kernel(const float* __restrict__ partial, float* __restrict__ xg)
{
    int b = blockIdx.x, c = threadIdx.x;
    float s = 0.f;
    const float* p = partial + ((size_t)b * 64) * 256 + c;
    for (int k = 0; k < 64; ++k) s += p[(size_t)k * 256];
    xg[b*256 + c] = s;
}

// --------------------------------------------------------------- f-MLP ----
__global__ void fmlp_kernel(const float* __restrict__ xg,
                            const float* __restrict__ Wf1, const float* __restrict__ bf1,
                            const float* __restrict__ Wf2, const float* __restrict__ bf2,
                            const float* __restrict__ Wf3, const float* __restrict__ bf3,
                            float* __restrict__ out)
{
    int b = blockIdx.x, tid = threadIdx.x;
    __shared__ float v0[256], v1[256], lgt[28];
    v0[tid] = xg[b*256 + tid];
    __syncthreads();
    {
        float s = bf1[tid];
        const float4* wr = reinterpret_cast<const float4*>(Wf1 + (size_t)tid * 256);
        for (int k4 = 0; k4 < 64; ++k4) {
            float4 wv = wr[k4];
            s += wv.x*v0[k4*4+0] + wv.y*v0[k4*4+1] + wv.z*v0[k4*4+2] + wv.w*v0[k4*4+3];
        }
        v1[tid] = fmaxf(s, 0.f);
    }
    __syncthreads();
    {
        float s = bf2[tid];
        const float4* wr = reinterpret_cast<const float4*>(Wf2 + (size_t)tid * 256);
        for (int k4 = 0; k4 < 64; ++k4) {
            float4 wv = wr[k4];
            s += wv.x*v1[k4*4+0] + wv.y*v1[k4*4+1] + wv.z*v1[k4*4+2] + wv.w*v1[k4*4+3];
        }
        v0[tid] = fmaxf(s, 0.f);
    }
    __syncthreads();
    if (tid < 28) {
        float s = bf3[tid];
        const float4* wr = reinterpret_cast<const float4*>(Wf3 + (size_t)tid * 256);
        for (int k4 = 0; k4 < 64; ++k4) {
            float4 wv = wr[k4];
            s += wv.x*v0[k4*4+0] + wv.y*v0[k4*4+1] + wv.z*v0[k4*4+2] + wv.w*v0[k4*4+3];
        }
        lgt[tid] = s;
    }
    __syncthreads();
    if (tid == 0) {
        float mx = -1e30f;
        for (int i = 0; i < 28; ++i) mx = fmaxf(mx, lgt[i]);
        float se = 0.f;
        for (int i = 0; i < 28; ++i) se += expf(lgt[i] - mx);
        float lse = mx + logf(se);
        for (int i = 0; i < 28; ++i) out[b*28 + i] = lgt[i] - lse;
    }
}

// ------------------------------------------------------------- launch -----
extern "C" void kernel_launch(void* const* d_in, const int* in_sizes, int n_in,
                              void* d_out, int out_size, void* d_ws, size_t ws_size,
                              hipStream_t stream)
{
    (void)in_sizes; (void)n_in; (void)out_size; (void)ws_size;
    const float* img = (const float*)d_in[0];
    const int*   qidx= (const int*)  d_in[1];
    const float* emb = (const float*)d_in[2];
    const float* Wih = (const float*)d_in[3];
    const float* Whh = (const float*)d_in[4];
    const float* bih = (const float*)d_in[5];
    const float* bhh = (const float*)d_in[6];
    const float* k1  = (const float*)d_in[7];  const float* cb1=(const float*)d_in[8];
    const float* g1  = (const float*)d_in[9];  const float* be1=(const float*)d_in[10];
    const float* k2  = (const float*)d_in[11]; const float* cb2=(const float*)d_in[12];
    const float* g2  = (const float*)d_in[13]; const float* be2=(const float*)d_in[14];
    const float* k3  = (const float*)d_in[15]; const float* cb3=(const float*)d_in[16];
    const float* g3  = (const float*)d_in[17]; const float* be3=(const float*)d_in[18];
    const float* k4  = (const float*)d_in[19]; const float* cb4=(const float*)d_in[20];
    const float* g4  = (const float*)d_in[21]; const float* be4=(const float*)d_in[22];
    const float* Wg1 = (const float*)d_in[23]; const float* bg1=(const float*)d_in[24];
    const float* Wg2 = (const float*)d_in[25]; const float* bg2=(const float*)d_in[26];
    const float* Wg3 = (const float*)d_in[27]; const float* bg3=(const float*)d_in[28];
    const float* Wg4 = (const float*)d_in[29]; const float* bg4=(const float*)d_in[30];
    const float* Wf1 = (const float*)d_in[31]; const float* bf1=(const float*)d_in[32];
    const float* Wf2 = (const float*)d_in[33]; const float* bf2=(const float*)d_in[34];
    const float* Wf3 = (const float*)d_in[35]; const float* bf3=(const float*)d_in[36];
    const float* h0  = (const float*)d_in[37]; const float* c0 =(const float*)d_in[38];
    float* out = (float*)d_out;

    // workspace carve-up (floats), all 16B aligned
    float* ws = (float*)d_ws;
    float* y1 = ws;   ws += 64*24*64*64;
    float* y2 = ws;   ws += 64*24*32*32;
    float* y3 = ws;   ws += 64*24*16*16;
    float* y4 = ws;   ws += 64*24*8*8;
    float* ab1 = ws;  ws += 48;
    float* ab2 = ws;  ws += 48;
    float* ab3 = ws;  ws += 48;
    float* ab4 = ws;  ws += 48;
    float* bnp = ws;  ws += 24*16*2;
    float* qst = ws;  ws += 64*128;
    float* xf  = ws;  ws += 64*64*26;
    float* Ai  = ws;  ws += 64*64*256;
    float* Aj  = ws;  ws += 64*64*256;
    float* Qb  = ws;  ws += 64*256;
    unsigned short* Wb2 = (unsigned short*)ws; ws += 65536/2;
    unsigned short* Wb3 = (unsigned short*)ws; ws += 65536/2;
    unsigned short* Wb4 = (unsigned short*)ws; ws += 65536/2;
    float* partial = ws; ws += 4096*256;
    float* xg  = ws;  ws += 64*256;

    lstm_kernel<<<64, 512, 0, stream>>>(qidx, emb, Wih, Whh, bih, bhh, h0, c0, qst);

    conv_kernel<<<(64*24*64*64 + 255)/256, 256, 0, stream>>>(img, k1, cb1, nullptr, y1, 3, 128, 128, 64, 64);
    bn_partial_kernel<<<dim3(24,16), 256, 0, stream>>>(y1, bnp, 64*64, 4);
    bn_final_kernel<<<1, 32, 0, stream>>>(bnp, g1, be1, ab1, 16, 64*64*64);
    conv_kernel<<<(64*24*32*32 + 255)/256, 256, 0, stream>>>(y1, k2, cb2, ab1, y2, 24, 64, 64, 32, 32);
    bn_partial_kernel<<<dim3(24,8), 256, 0, stream>>>(y2, bnp, 32*32, 8);
    bn_final_kernel<<<1, 32, 0, stream>>>(bnp, g2, be2, ab2, 8, 64*32*32);
    conv_kernel<<<(64*24*16*16 + 255)/256, 256, 0, stream>>>(y2, k3, cb3, ab2, y3, 24, 32, 32, 16, 16);
    bn_partial_kernel<<<dim3(24,4), 256, 0, stream>>>(y3, bnp, 16*16, 16);
    bn_final_kernel<<<1, 32, 0, stream>>>(bnp, g3, be3, ab3, 4, 64*16*16);
    conv_kernel<<<(64*24*8*8 + 255)/256, 256, 0, stream>>>(y3, k4, cb4, ab3, y4, 24, 16, 16, 8, 8);
    bn_partial_kernel<<<dim3(24,1), 256, 0, stream>>>(y4, bnp, 8*8, 64);
    bn_final_kernel<<<1, 32, 0, stream>>>(bnp, g4, be4, ab4, 1, 64*8*8);

    build_xf_kernel<<<64, 64, 0, stream>>>(y4, ab4, xf);
    aiajq_kernel<<<64, 256, 0, stream>>>(xf, qst, Wg1, bg1, Ai, Aj, Qb);

    cvt_bf16_kernel<<<256, 256, 0, stream>>>(Wg2, Wb2, 65536);
    cvt_bf16_kernel<<<256, 256, 0, stream>>>(Wg3, Wb3, 65536);
    cvt_bf16_kernel<<<256, 256, 0, stream>>>(Wg4, Wb4, 65536);

    gmlp_kernel<<<4096, 256, 0, stream>>>(Ai, Aj, Qb, Wb2, bg2, Wb3, bg3, Wb4, bg4, partial);
    reduce_partial_kernel<<<64, 256, 0, stream>>>(partial, xg);
    fmlp_kernel<<<64, 256, 0, stream>>>(xg, Wf1, bf1, Wf2, bf2, Wf3, bf3, out);
}

// Round 3
// 784.866 us; speedup vs baseline: 1.5933x; 1.0661x over previous
//
#include <hip/hip_runtime.h>
#include <math.h>

typedef __bf16 bf16x8 __attribute__((ext_vector_type(8)));
typedef float  f32x4  __attribute__((ext_vector_type(4)));

#define DEVFN __device__ __forceinline__

DEVFN unsigned short f2bf(float f) {
    union { float f; unsigned u; } v; v.f = f;
    unsigned r = v.u + 0x7FFFu + ((v.u >> 16) & 1u);   // RNE
    return (unsigned short)(r >> 16);
}
DEVFN float sigmoidf_(float x) { return 1.0f / (1.0f + expf(-x)); }

// ---------------------------------------------------------------- LSTM ----
__global__ void lstm_kernel(const int* __restrict__ qidx, const float* __restrict__ emb,
                            const float* __restrict__ Wih, const float* __restrict__ Whh,
                            const float* __restrict__ bih, const float* __restrict__ bhh,
                            const float* __restrict__ h0, const float* __restrict__ c0,
                            float* __restrict__ qst)
{
    int b = blockIdx.x, tid = threadIdx.x;
    __shared__ float hs[128], cs[128], xs[32], gs[512];
    if (tid < 128) { hs[tid] = h0[b*128 + tid]; cs[tid] = c0[b*128 + tid]; }
    float bsum = bih[tid] + bhh[tid];
    for (int t = 0; t < 18; ++t) {
        if (tid < 32) {
            int id = qidx[b*18 + t];
            xs[tid] = (id != 0) ? emb[id*32 + tid] : 0.0f;
        }
        __syncthreads();
        float g = bsum;
        const float* wi = Wih + tid*32;
        #pragma unroll
        for (int d = 0; d < 32; ++d) g += xs[d] * wi[d];
        const float* wh = Whh + tid*128;
        for (int d = 0; d < 128; ++d) g += hs[d] * wh[d];
        gs[tid] = g;
        __syncthreads();
        if (tid < 128) {
            float ig = sigmoidf_(gs[tid]);
            float fg = sigmoidf_(gs[128 + tid]);
            float gg = tanhf(gs[256 + tid]);
            float og = sigmoidf_(gs[384 + tid]);
            float cn = fg * cs[tid] + ig * gg;
            cs[tid] = cn;
            hs[tid] = og * tanhf(cn);
        }
        __syncthreads();
    }
    if (tid < 128) qst[b*128 + tid] = cs[tid];   // final CELL state
}

// ---------------------------------------------------------------- conv ----
// grid: (64*24, ceil(HW/256)); block fixed (b, co). BN scale folded into
// LDS weights; BN offset collapsed to 9 per-tap sums added once per valid
// tap (border-exact).
__global__ void conv_kernel(const float* __restrict__ in, const float* __restrict__ wk,
                            const float* __restrict__ cb, const float* __restrict__ ab,
                            float* __restrict__ out,
                            int Cin, int Hin, int Win, int Hout, int Wout)
{
    int cob = blockIdx.x;
    int co = cob % 24, b = cob / 24;
    int tid = threadIdx.x;
    __shared__ float sw[24*9];
    __shared__ float so9[9];
    __shared__ float bias;
    if (tid < Cin*9) {
        int ci = tid / 9, t = tid % 9;
        float a_ = ab ? ab[ci] : 1.0f;
        sw[tid] = wk[(co*Cin + ci)*9 + t] * a_;
    }
    if (tid < 9) {
        float s = 0.f;
        if (ab) {
            for (int ci = 0; ci < Cin; ++ci)
                s += ab[Cin + ci] * wk[(co*Cin + ci)*9 + tid];
        }
        so9[tid] = s;
    }
    if (tid == 0) bias = cb[co];
    __syncthreads();

    int HW = Hout * Wout;
    int pos = blockIdx.y * 256 + tid;
    if (pos >= HW) return;
    int ow = pos % Wout, oh = pos / Wout;

    float acc = bias;
    #pragma unroll
    for (int kh = 0; kh < 3; ++kh) {
        int ih = oh*2 + kh - 1;
        bool vh = (ih >= 0 && ih < Hin);
        #pragma unroll
        for (int kw = 0; kw < 3; ++kw) {
            int iw = ow*2 + kw - 1;
            if (vh && iw >= 0 && iw < Win) acc += so9[kh*3 + kw];
        }
    }
    const float* ipb = in + ((size_t)b * Cin) * Hin * Win;
    for (int ci = 0; ci < Cin; ++ci) {
        const float* ip = ipb + (size_t)ci * Hin * Win;
        const float* swp = sw + ci*9;
        #pragma unroll
        for (int kh = 0; kh < 3; ++kh) {
            int ih = oh*2 + kh - 1;
            if (ih < 0 || ih >= Hin) continue;
            #pragma unroll
            for (int kw = 0; kw < 3; ++kw) {
                int iw = ow*2 + kw - 1;
                if (iw < 0 || iw >= Win) continue;
                acc += ip[ih*Win + iw] * swp[kh*3 + kw];
            }
        }
    }
    out[((size_t)(b*24 + co)) * HW + pos] = fmaxf(acc, 0.0f);
}

// ---- BN stats, two-stage deterministic reduction -------------------------
__global__ void bn_partial_kernel(const float* __restrict__ y, float* __restrict__ part,
                                  int HW, int nb)
{
    int c = blockIdx.x;
    int s = blockIdx.y;
    int S = gridDim.y;
    int tid = threadIdx.x;
    int n4 = HW >> 2;
    float sum = 0.f, sum2 = 0.f;
    for (int b = s * nb; b < (s + 1) * nb; ++b) {
        const float4* p = reinterpret_cast<const float4*>(y + ((size_t)(b*24 + c)) * HW);
        for (int i = tid; i < n4; i += 256) {
            float4 v = p[i];
            sum  += v.x + v.y + v.z + v.w;
            sum2 += v.x*v.x + v.y*v.y + v.z*v.z + v.w*v.w;
        }
    }
    __shared__ float rs[256], rs2[256];
    rs[tid] = sum; rs2[tid] = sum2;
    __syncthreads();
    for (int st = 128; st > 0; st >>= 1) {
        if (tid < st) { rs[tid] += rs[tid + st]; rs2[tid] += rs2[tid + st]; }
        __syncthreads();
    }
    if (tid == 0) {
        part[(c * S + s) * 2]     = rs[0];
        part[(c * S + s) * 2 + 1] = rs2[0];
    }
}

__global__ void bn_final_kernel(const float* __restrict__ part, const float* __restrict__ gamma,
                                const float* __restrict__ beta, float* __restrict__ ab,
                                int S, int N)
{
    int c = threadIdx.x;
    if (c >= 24) return;
    float s = 0.f, s2 = 0.f;
    for (int i = 0; i < S; ++i) { s += part[(c*S + i)*2]; s2 += part[(c*S + i)*2 + 1]; }
    float m = s / N;
    float v = s2 / N - m * m;               // biased var
    float r = rsqrtf(v + 1e-5f);
    float a = gamma[c] * r;
    ab[c] = a; ab[24 + c] = beta[c] - m * a;
}

// --------------------------------------------------------------- xf -------
__global__ void build_xf_kernel(const float* __restrict__ y4, const float* __restrict__ ab4,
                                float* __restrict__ xf)
{
    int b = blockIdx.x, p = threadIdx.x;          // 64 x 64
    float* o = xf + ((size_t)(b*64 + p)) * 26;
    for (int c = 0; c < 24; ++c)
        o[c] = y4[((size_t)(b*24 + c)) * 64 + p] * ab4[c] + ab4[24 + c];
    o[24] = ((float)p / 8.0f - 4.0f) * 0.25f;     // python true division i/D
    o[25] = ((float)(p % 8) - 4.0f) * 0.25f;      // integer i%D
}

// Ai[b,j,c], Aj[b,j,c], Q[b,c] — decomposed first g-layer
__global__ void aiajq_kernel(const float* __restrict__ xf, const float* __restrict__ qst,
                             const float* __restrict__ Wg1, const float* __restrict__ bg1,
                             float* __restrict__ Ai, float* __restrict__ Aj, float* __restrict__ Q)
{
    int b = blockIdx.x, c = threadIdx.x;          // 64 x 256
    __shared__ float xfl[64 * 26];
    __shared__ float qv[128];
    for (int i = c; i < 64*26; i += 256) xfl[i] = xf[(size_t)b*64*26 + i];
    if (c < 128) qv[c] = qst[b*128 + c];
    __syncthreads();
    const float* w = Wg1 + (size_t)c * 180;
    float wa[26], wb[26];
    #pragma unroll
    for (int d = 0; d < 26; ++d) { wa[d] = w[d]; wb[d] = w[26 + d]; }
    float q = bg1[c];
    for (int d = 0; d < 128; ++d) q += qv[d] * w[52 + d];
    Q[b*256 + c] = q;
    for (int j = 0; j < 64; ++j) {
        const float* xr = xfl + j*26;
        float sa = 0.f, sb = 0.f;
        #pragma unroll
        for (int d = 0; d < 26; ++d) { sa += xr[d]*wa[d]; sb += xr[d]*wb[d]; }
        Ai[((size_t)(b*64 + j))*256 + c] = sa;
        Aj[((size_t)(b*64 + j))*256 + c] = sb;
    }
}

__global__ void cvt_bf16_kernel(const float* __restrict__ src, unsigned short* __restrict__ dst, int n)
{
    int i = blockIdx.x * 256 + threadIdx.x;
    if (i < n) dst[i] = f2bf(src[i]);
}

// --------------------------------------------------------------- g-MLP ----
// one block per (b,k): 64 pair-rows, 3 fused bf16-MFMA layers, column-sum
// out. SINGLE LDS buffer (in-place layer swap with 2 barriers) -> 33.8 KB
// -> 4 blocks/CU -> 4 waves/SIMD.
__launch_bounds__(256, 4)
__global__ void gmlp_kernel(const float* __restrict__ Ai, const float* __restrict__ Aj,
                            const float* __restrict__ Q,
                            const unsigned short* __restrict__ Wb2, const float* __restrict__ bg2,
                            const unsigned short* __restrict__ Wb3, const float* __restrict__ bg3,
                            const unsigned short* __restrict__ Wb4, const float* __restrict__ bg4,
                            float* __restrict__ partial)
{
    constexpr int LDP = 264;                       // +8 pad
    __shared__ __align__(16) unsigned short buf[64 * LDP];
    int tid = threadIdx.x;
    int blk = blockIdx.x;
    int b = blk >> 6;

    // ---- h1 = relu(Ai[b,j] + Aj[b,k] + Q[b]) -> buf (bf16)
    float ajq = Aj[(size_t)blk * 256 + tid] + Q[b*256 + tid];
    const float* aip = Ai + ((size_t)b * 64) * 256 + tid;
    for (int j = 0; j < 64; ++j) {
        float v = aip[(size_t)j * 256] + ajq;
        buf[j * LDP + tid] = f2bf(fmaxf(v, 0.f));
    }
    __syncthreads();

    int l = tid & 63, w = tid >> 6;
    int lr = l & 15, lg = l >> 4;
    int wcol = w * 64;                              // wave's 64-col slice

    const unsigned short* Ws[3] = {Wb2, Wb3, Wb4};
    const float* Bs[3] = {bg2, bg3, bg4};

    for (int layer = 0; layer < 3; ++layer) {
        const unsigned short* W = Ws[layer];
        const float* bias = Bs[layer];
        f32x4 acc[4][4];
        #pragma unroll
        for (int i = 0; i < 4; ++i)
            #pragma unroll
            for (int j2 = 0; j2 < 4; ++j2) { f32x4 z = {0.f,0.f,0.f,0.f}; acc[i][j2] = z; }

        #pragma unroll
        for (int kk = 0; kk < 256; kk += 32) {
            int ko = kk + lg * 8;
            bf16x8 aF[4], bF[4];
            #pragma unroll
            for (int rg = 0; rg < 4; ++rg)
                aF[rg] = *reinterpret_cast<const bf16x8*>(&buf[(rg*16 + lr) * LDP + ko]);
            #pragma unroll
            for (int cg = 0; cg < 4; ++cg)
                bF[cg] = *reinterpret_cast<const bf16x8*>(&W[(size_t)(wcol + cg*16 + lr) * 256 + ko]);
            #pragma unroll
            for (int rg = 0; rg < 4; ++rg)
                #pragma unroll
                for (int cg = 0; cg < 4; ++cg)
                    acc[rg][cg] = __builtin_amdgcn_mfma_f32_16x16x32_bf16(aF[rg], bF[cg], acc[rg][cg], 0, 0, 0);
        }

        if (layer < 2) {
            __syncthreads();                        // all reads of buf done
            #pragma unroll
            for (int cg = 0; cg < 4; ++cg) {
                int col = wcol + cg*16 + lr;
                float bc = bias[col];
                #pragma unroll
                for (int rg = 0; rg < 4; ++rg)
                    #pragma unroll
                    for (int r = 0; r < 4; ++r) {
                        int row = rg*16 + lg*4 + r;   // C/D: row=(lane>>4)*4+reg
                        buf[row * LDP + col] = f2bf(fmaxf(acc[rg][cg][r] + bc, 0.f));
                    }
            }
            __syncthreads();                        // writes visible
        } else {
            // layer 4: relu then column-sum over the block's 64 rows
            #pragma unroll
            for (int cg = 0; cg < 4; ++cg) {
                int col = wcol + cg*16 + lr;
                float bc = bias[col];
                float cssum = 0.f;
                #pragma unroll
                for (int rg = 0; rg < 4; ++rg)
                    #pragma unroll
                    for (int r = 0; r < 4; ++r)
                        cssum += fmaxf(acc[rg][cg][r] + bc, 0.f);
                cssum += __shfl_xor(cssum, 16, 64);
                cssum += __shfl_xor(cssum, 32, 64);
                if (lg == 0)
                    partial[(size_t)blk * 256 + col] = cssum;
            }
        }
    }
}

__global__ void reduce_partial_kernel(const float* __restrict__ partial, float* __restrict__ xg)
{
    int b = blockIdx.x, c = threadIdx.x;
    float s0 = 0.f, s1 = 0.f, s2 = 0.f, s3 = 0.f;
    const float* p = partial + ((size_t)b * 64) * 256 + c;
    for (int k = 0; k < 64; k += 4) {               // 4 independent chains (MLP)
        s0 += p[(size_t)(k+0) * 256];
        s1 += p[(size_t)(k+1) * 256];
        s2 += p[(size_t)(k+2) * 256];
        s3 += p[(size_t)(k+3) * 256];
    }
    xg[b*256 + c] = (s0 + s1) + (s2 + s3);
}

// --------------------------------------------------------------- f-MLP ----
__global__ void fmlp_kernel(const float* __restrict__ xg,
                            const float* __restrict__ Wf1, const float* __restrict__ bf1,
                            const float* __restrict__ Wf2, const float* __restrict__ bf2,
                            const float* __restrict__ Wf3, const float* __restrict__ bf3,
                            float* __restrict__ out)
{
    int b = blockIdx.x, tid = threadIdx.x;
    __shared__ float v0[256], v1[256], lgt[28];
    v0[tid] = xg[b*256 + tid];
    __syncthreads();
    {
        float s = bf1[tid];
        const float4* wr = reinterpret_cast<const float4*>(Wf1 + (size_t)tid * 256);
        for (int k4 = 0; k4 < 64; ++k4) {
            float4 wv = wr[k4];
            s += wv.x*v0[k4*4+0] + wv.y*v0[k4*4+1] + wv.z*v0[k4*4+2] + wv.w*v0[k4*4+3];
        }
        v1[tid] = fmaxf(s, 0.f);
    }
    __syncthreads();
    {
        float s = bf2[tid];
        const float4* wr = reinterpret_cast<const float4*>(Wf2 + (size_t)tid * 256);
        for (int k4 = 0; k4 < 64; ++k4) {
            float4 wv = wr[k4];
            s += wv.x*v1[k4*4+0] + wv.y*v1[k4*4+1] + wv.z*v1[k4*4+2] + wv.w*v1[k4*4+3];
        }
        v0[tid] = fmaxf(s, 0.f);
    }
    __syncthreads();
    if (tid < 28) {
        float s = bf3[tid];
        const float4* wr = reinterpret_cast<const float4*>(Wf3 + (size_t)tid * 256);
        for (int k4 = 0; k4 < 64; ++k4) {
            float4 wv = wr[k4];
            s += wv.x*v0[k4*4+0] + wv.y*v0[k4*4+1] + wv.z*v0[k4*4+2] + wv.w*v0[k4*4+3];
        }
        lgt[tid] = s;
    }
    __syncthreads();
    if (tid == 0) {
        float mx = -1e30f;
        for (int i = 0; i < 28; ++i) mx = fmaxf(mx, lgt[i]);
        float se = 0.f;
        for (int i = 0; i < 28; ++i) se += expf(lgt[i] - mx);
        float lse = mx + logf(se);
        for (int i = 0; i < 28; ++i) out[b*28 + i] = lgt[i] - lse;
    }
}

// ------------------------------------------------------------- launch -----
extern "C" void kernel_launch(void* const* d_in, const int* in_sizes, int n_in,
                              void* d_out, int out_size, void* d_ws, size_t ws_size,
                              hipStream_t stream)
{
    (void)in_sizes; (void)n_in; (void)out_size; (void)ws_size;
    const float* img = (const float*)d_in[0];
    const int*   qidx= (const int*)  d_in[1];
    const float* emb = (const float*)d_in[2];
    const float* Wih = (const float*)d_in[3];
    const float* Whh = (const float*)d_in[4];
    const float* bih = (const float*)d_in[5];
    const float* bhh = (const float*)d_in[6];
    const float* k1  = (const float*)d_in[7];  const float* cb1=(const float*)d_in[8];
    const float* g1  = (const float*)d_in[9];  const float* be1=(const float*)d_in[10];
    const float* k2  = (const float*)d_in[11]; const float* cb2=(const float*)d_in[12];
    const float* g2  = (const float*)d_in[13]; const float* be2=(const float*)d_in[14];
    const float* k3  = (const float*)d_in[15]; const float* cb3=(const float*)d_in[16];
    const float* g3  = (const float*)d_in[17]; const float* be3=(const float*)d_in[18];
    const float* k4  = (const float*)d_in[19]; const float* cb4=(const float*)d_in[20];
    const float* g4  = (const float*)d_in[21]; const float* be4=(const float*)d_in[22];
    const float* Wg1 = (const float*)d_in[23]; const float* bg1=(const float*)d_in[24];
    const float* Wg2 = (const float*)d_in[25]; const float* bg2=(const float*)d_in[26];
    const float* Wg3 = (const float*)d_in[27]; const float* bg3=(const float*)d_in[28];
    const float* Wg4 = (const float*)d_in[29]; const float* bg4=(const float*)d_in[30];
    const float* Wf1 = (const float*)d_in[31]; const float* bf1=(const float*)d_in[32];
    const float* Wf2 = (const float*)d_in[33]; const float* bf2=(const float*)d_in[34];
    const float* Wf3 = (const float*)d_in[35]; const float* bf3=(const float*)d_in[36];
    const float* h0  = (const float*)d_in[37]; const float* c0 =(const float*)d_in[38];
    float* out = (float*)d_out;

    // workspace carve-up (floats), all 16B aligned
    float* ws = (float*)d_ws;
    float* y1 = ws;   ws += 64*24*64*64;
    float* y2 = ws;   ws += 64*24*32*32;
    float* y3 = ws;   ws += 64*24*16*16;
    float* y4 = ws;   ws += 64*24*8*8;
    float* ab1 = ws;  ws += 48;
    float* ab2 = ws;  ws += 48;
    float* ab3 = ws;  ws += 48;
    float* ab4 = ws;  ws += 48;
    float* bnp = ws;  ws += 24*16*2;
    float* qst = ws;  ws += 64*128;
    float* xf  = ws;  ws += 64*64*26;
    float* Ai  = ws;  ws += 64*64*256;
    float* Aj  = ws;  ws += 64*64*256;
    float* Qb  = ws;  ws += 64*256;
    unsigned short* Wb2 = (unsigned short*)ws; ws += 65536/2;
    unsigned short* Wb3 = (unsigned short*)ws; ws += 65536/2;
    unsigned short* Wb4 = (unsigned short*)ws; ws += 65536/2;
    float* partial = ws; ws += 4096*256;
    float* xg  = ws;  ws += 64*256;

    lstm_kernel<<<64, 512, 0, stream>>>(qidx, emb, Wih, Whh, bih, bhh, h0, c0, qst);

    conv_kernel<<<dim3(64*24, 16), 256, 0, stream>>>(img, k1, cb1, nullptr, y1, 3, 128, 128, 64, 64);
    bn_partial_kernel<<<dim3(24,16), 256, 0, stream>>>(y1, bnp, 64*64, 4);
    bn_final_kernel<<<1, 32, 0, stream>>>(bnp, g1, be1, ab1, 16, 64*64*64);
    conv_kernel<<<dim3(64*24, 4), 256, 0, stream>>>(y1, k2, cb2, ab1, y2, 24, 64, 64, 32, 32);
    bn_partial_kernel<<<dim3(24,8), 256, 0, stream>>>(y2, bnp, 32*32, 8);
    bn_final_kernel<<<1, 32, 0, stream>>>(bnp, g2, be2, ab2, 8, 64*32*32);
    conv_kernel<<<dim3(64*24, 1), 256, 0, stream>>>(y2, k3, cb3, ab2, y3, 24, 32, 32, 16, 16);
    bn_partial_kernel<<<dim3(24,4), 256, 0, stream>>>(y3, bnp, 16*16, 16);
    bn_final_kernel<<<1, 32, 0, stream>>>(bnp, g3, be3, ab3, 4, 64*16*16);
    conv_kernel<<<dim3(64*24, 1), 256, 0, stream>>>(y3, k4, cb4, ab3, y4, 24, 16, 16, 8, 8);
    bn_partial_kernel<<<dim3(24,1), 256, 0, stream>>>(y4, bnp, 8*8, 64);
    bn_final_kernel<<<1, 32, 0, stream>>>(bnp, g4, be4, ab4, 1, 64*8*8);

    build_xf_kernel<<<64, 64, 0, stream>>>(y4, ab4, xf);
    aiajq_kernel<<<64, 256, 0, stream>>>(xf, qst, Wg1, bg1, Ai, Aj, Qb);

    cvt_bf16_kernel<<<256, 256, 0, stream>>>(Wg2, Wb2, 65536);
    cvt_bf16_kernel<<<256, 256, 0, stream>>>(Wg3, Wb3, 65536);
    cvt_bf16_kernel<<<256, 256, 0, stream>>>(Wg4, Wb4, 65536);

    gmlp_kernel<<<4096, 256, 0, stream>>>(Ai, Aj, Qb, Wb2, bg2, Wb3, bg3, Wb4, bg4, partial);
    reduce_partial_kernel<<<64, 256, 0, stream>>>(partial, xg);
    fmlp_kernel<<<64, 256, 0, stream>>>(xg, Wf1, bf1, Wf2, bf2, Wf3, bf3, out);
}